// Round 1
// baseline (1009.724 us; speedup 1.0000x reference)
//
#include <hip/hip_runtime.h>

// Boosted neural LDPC min-sum decoder, MI355X.
// Sizes fixed by setup_inputs(): B=32, Z=384, N=68, M=46, dc=7, E=322, iters=8.
#define B_   32
#define Z_   384
#define N_   68
#define M_   46
#define DC_  7
#define E_   (M_ * DC_)      // 322
#define NT   1024
#define INIT_STATE ((16u << 10) | (16u << 15))   // q1=0, q2=0, signs=0, first=0

// state word layout (20 bits):
//  [0:6]   neg bits per edge j (v2c < 0)
//  [7:9]   index of first min edge
//  [10:14] q1*2 + 16  (quantized w*min1, in half-steps, range [-15,15])
//  [15:19] q2*2 + 16
__device__ __forceinline__ int decode2(unsigned st, int j) {
    int neg   = (st >> j) & 1;
    int q1    = (int)((st >> 10) & 31) - 16;
    int q2    = (int)((st >> 15) & 31) - 16;
    int first = (int)((st >> 7) & 7);
    int q     = (j == first) ? q2 : q1;
    int par   = (__popc(st & 127u) - neg) & 1;   // parity of other edges' signs
    return par ? -q : q;                          // message * 2 (exact int)
}

__global__ __launch_bounds__(NT)
void ldpc_decode_kernel(const float* __restrict__ xa,
                        const float* __restrict__ cw,
                        const int*   __restrict__ vn_idx,
                        const int*   __restrict__ shifts,
                        float* out, int iters)
{
    __shared__ short tot[Z_ * N_];     // per-variable totals, in half-step units (exact)
    __shared__ int   evs[E_];          // vn | (shift << 7)
    __shared__ int   offs[N_ + 1];     // CSR offsets per variable
    __shared__ int   lists[E_];        // per-variable edge recs: s | (m<<9) | (j<<15)
    __shared__ float wlds[32];

    const int tid = threadIdx.x;
    const int b   = blockIdx.x;
    const float* xab = xa + (size_t)b * (Z_ * N_);
    float* outb = out + (size_t)b * (N_ * Z_);
    // Check-node state lives in this block's own output slice until the final write.
    int* stateg = (int*)outb;          // Z_*M_ = 17664 ints  <  N_*Z_ = 26112 floats

    // ---- build edge tables ----
    if (tid < E_) evs[tid] = vn_idx[tid] | (shifts[tid] << 7);
    if (tid < iters && tid < 32) wlds[tid] = cw[tid];
    __syncthreads();
    if (tid < N_) {
        int c = 0;
        for (int e = 0; e < E_; ++e) c += ((evs[e] & 127) == tid);
        offs[tid + 1] = c;
    }
    if (tid == 0) offs[0] = 0;
    __syncthreads();
    if (tid == 0) {
        for (int n = 0; n < N_; ++n) offs[n + 1] += offs[n];
    }
    __syncthreads();
    if (tid < N_) {
        int p = offs[tid];
        for (int e = 0; e < E_; ++e) {
            int rec = evs[e];
            if ((rec & 127) == tid) {
                int s = rec >> 7;
                lists[p++] = s | ((e / DC_) << 9) | ((e % DC_) << 15);
            }
        }
    }
    // ---- init state (c2v = 0) ----
    for (int i = tid; i < Z_ * M_; i += NT) stateg[i] = (int)INIT_STATE;
    __syncthreads();

    for (int it = 0; it < iters; ++it) {
        // ---- pass A: tot[z,n] = sum of incoming c2v (exact int, half-steps) ----
        for (int i = tid; i < Z_ * N_; i += NT) {
            int z = i / N_;
            int n = i - z * N_;
            int t2 = 0;
            int kend = offs[n + 1];
            for (int k = offs[n]; k < kend; ++k) {
                int rec = lists[k];
                int s = rec & 511;
                int m = (rec >> 9) & 63;
                int j = rec >> 15;
                int zs = z - s; if (zs < 0) zs += Z_;
                t2 += decode2((unsigned)stateg[zs * M_ + m], j);
            }
            tot[i] = (short)t2;
        }
        __syncthreads();

        // ---- pass B: check-node update (reads ONLY its own old state word) ----
        const float w = wlds[it];
        for (int i = tid; i < Z_ * M_; i += NT) {
            int z = i / M_;
            int m = i - z * M_;
            unsigned st = (unsigned)stateg[i];
            float m1 = 1e30f, m2 = 1e30f;
            int f = 0, negb = 0;
            #pragma unroll
            for (int j = 0; j < DC_; ++j) {
                int rec = evs[m * DC_ + j];
                int vn = rec & 127;
                int s  = rec >> 7;
                int zr = z + s; if (zr >= Z_) zr -= Z_;
                int c2 = decode2(st, j);
                int idx = zr * N_ + vn;
                // identical operand order to JAX: (llr + tot) - c2v, then clip
                float v = (xab[idx] + 0.5f * (float)tot[idx]) - 0.5f * (float)c2;
                v = fminf(fmaxf(v, -20.0f), 20.0f);
                negb |= (v < 0.0f) << j;
                float a = fabsf(v);
                if (a < m1) { m2 = m1; m1 = a; f = j; }
                else if (a < m2) { m2 = a; }
            }
            // quantize-STE forward: clip(rint(2*w*min)/2, +-7.5), stored as int*2
            float r1 = fminf(fmaxf(rintf(w * m1 * 2.0f), -15.0f), 15.0f);
            float r2 = fminf(fmaxf(rintf(w * m2 * 2.0f), -15.0f), 15.0f);
            int q1 = (int)r1 + 16;
            int q2 = (int)r2 + 16;
            stateg[i] = (int)(unsigned)(negb | (f << 7) | (q1 << 10) | (q2 << 15));
        }
        __syncthreads();
    }

    // ---- final tot from last state ----
    for (int i = tid; i < Z_ * N_; i += NT) {
        int z = i / N_;
        int n = i - z * N_;
        int t2 = 0;
        int kend = offs[n + 1];
        for (int k = offs[n]; k < kend; ++k) {
            int rec = lists[k];
            int s = rec & 511;
            int m = (rec >> 9) & 63;
            int j = rec >> 15;
            int zs = z - s; if (zs < 0) zs += Z_;
            t2 += decode2((unsigned)stateg[zs * M_ + m], j);
        }
        tot[i] = (short)t2;
    }
    __syncthreads();

    // ---- output: out[b, n*Z + z] = xa[b,z,n] + tot (overwrites the state scratch) ----
    for (int i = tid; i < N_ * Z_; i += NT) {
        int n = i / Z_;
        int z = i - n * Z_;
        outb[i] = xab[z * N_ + n] + 0.5f * (float)tot[z * N_ + n];
    }
}

extern "C" void kernel_launch(void* const* d_in, const int* in_sizes, int n_in,
                              void* d_out, int out_size, void* d_ws, size_t ws_size,
                              hipStream_t stream) {
    const float* xa = (const float*)d_in[0];
    const float* cw = (const float*)d_in[1];
    const int* vn   = (const int*)d_in[2];
    // d_in[3] = cn_idx: layout is repeat(arange(M), dc) by construction — implicit.
    const int* sh   = (const int*)d_in[4];
    // d_in[5] = M (device scalar) — fixed at 46 for this problem.
    int iters = in_sizes[1];

    hipLaunchKernelGGL(ldpc_decode_kernel, dim3(B_), dim3(NT), 0, stream,
                       xa, cw, vn, sh, (float*)d_out, iters);
}

// Round 2
// 813.994 us; speedup vs baseline: 1.2405x; 1.2405x over previous
//
#include <hip/hip_runtime.h>
#include <hip/hip_cooperative_groups.h>

namespace cg = cooperative_groups;

// Boosted neural LDPC min-sum decoder, MI355X.
// Sizes fixed by setup_inputs(): B=32, Z=384, N=68, M=46, dc=7, E=322, iters=8.
#define B_   32
#define Z_   384
#define N_   68
#define M_   46
#define DC_  7
#define E_   (M_ * DC_)      // 322
#define NT   1024
#define CHUNKS 8
#define ZN   (Z_ * N_)       // 26112
#define ZM   (Z_ * M_)       // 17664
#define ZN_C (ZN / CHUNKS)   // 3264
#define ZM_C (ZM / CHUNKS)   // 2208
#define INIT_STATE ((16u << 10) | (16u << 15))   // q1=0, q2=0, signs=0, first=0

// state word layout (20 bits):
//  [0:6]   neg bits per edge j (v2c < 0)
//  [7:9]   index of first min edge
//  [10:14] q1*2 + 16  (quantized w*min1, in half-steps, range [-15,15])
//  [15:19] q2*2 + 16
__device__ __forceinline__ int decode2(unsigned st, int j) {
    int neg   = (st >> j) & 1;
    int q1    = (int)((st >> 10) & 31) - 16;
    int q2    = (int)((st >> 15) & 31) - 16;
    int first = (int)((st >> 7) & 7);
    int q     = (j == first) ? q2 : q1;
    int par   = (__popc(st & 127u) - neg) & 1;   // parity of other edges' signs
    return par ? -q : q;                          // message * 2 (exact int)
}

// ---- per-block edge-table build (identical tables in every block's LDS) ----
__device__ __forceinline__ void build_tables(const int* __restrict__ vn_idx,
                                             const int* __restrict__ shifts,
                                             const float* __restrict__ cw, int iters,
                                             int* evs, int* offs, int* lists, float* wlds) {
    const int tid = threadIdx.x;
    if (tid < E_) evs[tid] = vn_idx[tid] | (shifts[tid] << 7);
    if (tid < iters && tid < 8) wlds[tid] = cw[tid];
    __syncthreads();
    if (tid < N_) {
        int c = 0;
        for (int e = 0; e < E_; ++e) c += ((evs[e] & 127) == tid);
        offs[tid + 1] = c;
    }
    if (tid == 0) offs[0] = 0;
    __syncthreads();
    if (tid == 0) {
        for (int n = 0; n < N_; ++n) offs[n + 1] += offs[n];
    }
    __syncthreads();
    if (tid < N_) {
        int p = offs[tid];
        for (int e = 0; e < E_; ++e) {
            int rec = evs[e];
            if ((rec & 127) == tid) {
                int s = rec >> 7;
                lists[p++] = s | ((e / DC_) << 9) | ((e % DC_) << 15);
            }
        }
    }
    __syncthreads();
}

// ==================== cooperative multi-block kernel ====================
// 256 blocks: block g handles batch b = g&31, chunk c = g>>5.
// All 8 blocks of batch b land on XCD b%8 (round-robin dispatch) -> L2 locality.
// lt[b][z*N+n] = fl(llr + 0.5*tot)  lives in d_ws (fp32).
// state[b][z*M+m] lives in batch b's slice of d_out (17664 ints < 26112 floats).
__global__ __launch_bounds__(NT)
void ldpc_coop_kernel(const float* __restrict__ xa,
                      const float* __restrict__ cw,
                      const int*   __restrict__ vn_idx,
                      const int*   __restrict__ shifts,
                      float* out, float* lt_g, int iters)
{
    __shared__ int   evs[E_];
    __shared__ int   offs[N_ + 1];
    __shared__ int   lists[E_];
    __shared__ float wlds[8];

    cg::grid_group grid = cg::this_grid();
    const int tid = threadIdx.x;
    const int g   = blockIdx.x;
    const int b   = g & 31;
    const int c   = g >> 5;

    const float* xab = xa + (size_t)b * ZN;
    float* ltb  = lt_g + (size_t)b * ZN;
    float* outb = out + (size_t)b * ZN;
    int* stb = (int*)outb;             // check state scratch inside output slice

    build_tables(vn_idx, shifts, cw, iters, evs, offs, lists, wlds);

    // init state (c2v = 0) for this block's share
    for (int i = c * ZM_C + tid; i < (c + 1) * ZM_C; i += NT) stb[i] = (int)INIT_STATE;
    grid.sync();

    for (int it = 0; it <= iters; ++it) {
        // ---- pass A: lt[z,n] = fl(llr + 0.5 * tot)   (tot exact int, half-steps)
        for (int i = c * ZN_C + tid; i < (c + 1) * ZN_C; i += NT) {
            int z = i / N_;
            int n = i - z * N_;
            int t2 = 0;
            int kend = offs[n + 1];
            for (int k = offs[n]; k < kend; ++k) {
                int rec = lists[k];
                int s = rec & 511;
                int m = (rec >> 9) & 63;
                int j = rec >> 15;
                int zs = z - s; if (zs < 0) zs += Z_;
                t2 += decode2((unsigned)stb[zs * M_ + m], j);
            }
            ltb[i] = xab[i] + 0.5f * (float)t2;
        }
        grid.sync();
        if (it == iters) break;

        // ---- pass B: check-node update (reads lt + its OWN old state word) ----
        const float w = wlds[it];
        for (int i = c * ZM_C + tid; i < (c + 1) * ZM_C; i += NT) {
            int z = i / M_;
            int m = i - z * M_;
            unsigned st = (unsigned)stb[i];
            float m1 = 1e30f, m2 = 1e30f;
            int f = 0, negb = 0;
            #pragma unroll
            for (int j = 0; j < DC_; ++j) {
                int rec = evs[m * DC_ + j];
                int vn = rec & 127;
                int s  = rec >> 7;
                int zr = z + s; if (zr >= Z_) zr -= Z_;
                int c2 = decode2(st, j);
                // identical operand order to JAX: fl(fl(llr + tot) - c2v), then clip
                float v = ltb[zr * N_ + vn] - 0.5f * (float)c2;
                v = fminf(fmaxf(v, -20.0f), 20.0f);
                negb |= (v < 0.0f) << j;
                float a = fabsf(v);
                if (a < m1) { m2 = m1; m1 = a; f = j; }
                else if (a < m2) { m2 = a; }
            }
            // quantize-STE forward: clip(rint(2*w*min)/2, +-7.5), stored as int*2
            float r1 = fminf(fmaxf(rintf(w * m1 * 2.0f), -15.0f), 15.0f);
            float r2 = fminf(fmaxf(rintf(w * m2 * 2.0f), -15.0f), 15.0f);
            int q1 = (int)r1 + 16;
            int q2 = (int)r2 + 16;
            stb[i] = (int)(unsigned)(negb | (f << 7) | (q1 << 10) | (q2 << 15));
        }
        grid.sync();
    }

    // ---- output: out[b, n*Z + z] = lt[b, z*N + n]  (overwrites the state scratch)
    for (int i = c * ZN_C + tid; i < (c + 1) * ZN_C; i += NT) {
        int n = i / Z_;
        int z = i - n * Z_;
        outb[i] = ltb[z * N_ + n];
    }
}

// ==================== fallback: round-1 single-block-per-batch kernel ====================
__global__ __launch_bounds__(NT)
void ldpc_decode_kernel(const float* __restrict__ xa,
                        const float* __restrict__ cw,
                        const int*   __restrict__ vn_idx,
                        const int*   __restrict__ shifts,
                        float* out, int iters)
{
    __shared__ short tot[ZN];
    __shared__ int   evs[E_];
    __shared__ int   offs[N_ + 1];
    __shared__ int   lists[E_];
    __shared__ float wlds[8];

    const int tid = threadIdx.x;
    const int b   = blockIdx.x;
    const float* xab = xa + (size_t)b * ZN;
    float* outb = out + (size_t)b * ZN;
    int* stateg = (int*)outb;

    build_tables(vn_idx, shifts, cw, iters, evs, offs, lists, wlds);

    for (int i = tid; i < ZM; i += NT) stateg[i] = (int)INIT_STATE;
    __syncthreads();

    for (int it = 0; it < iters; ++it) {
        for (int i = tid; i < ZN; i += NT) {
            int z = i / N_;
            int n = i - z * N_;
            int t2 = 0;
            int kend = offs[n + 1];
            for (int k = offs[n]; k < kend; ++k) {
                int rec = lists[k];
                int s = rec & 511;
                int m = (rec >> 9) & 63;
                int j = rec >> 15;
                int zs = z - s; if (zs < 0) zs += Z_;
                t2 += decode2((unsigned)stateg[zs * M_ + m], j);
            }
            tot[i] = (short)t2;
        }
        __syncthreads();

        const float w = wlds[it];
        for (int i = tid; i < ZM; i += NT) {
            int z = i / M_;
            int m = i - z * M_;
            unsigned st = (unsigned)stateg[i];
            float m1 = 1e30f, m2 = 1e30f;
            int f = 0, negb = 0;
            #pragma unroll
            for (int j = 0; j < DC_; ++j) {
                int rec = evs[m * DC_ + j];
                int vn = rec & 127;
                int s  = rec >> 7;
                int zr = z + s; if (zr >= Z_) zr -= Z_;
                int c2 = decode2(st, j);
                int idx = zr * N_ + vn;
                float v = (xab[idx] + 0.5f * (float)tot[idx]) - 0.5f * (float)c2;
                v = fminf(fmaxf(v, -20.0f), 20.0f);
                negb |= (v < 0.0f) << j;
                float a = fabsf(v);
                if (a < m1) { m2 = m1; m1 = a; f = j; }
                else if (a < m2) { m2 = a; }
            }
            float r1 = fminf(fmaxf(rintf(w * m1 * 2.0f), -15.0f), 15.0f);
            float r2 = fminf(fmaxf(rintf(w * m2 * 2.0f), -15.0f), 15.0f);
            int q1 = (int)r1 + 16;
            int q2 = (int)r2 + 16;
            stateg[i] = (int)(unsigned)(negb | (f << 7) | (q1 << 10) | (q2 << 15));
        }
        __syncthreads();
    }

    for (int i = tid; i < ZN; i += NT) {
        int z = i / N_;
        int n = i - z * N_;
        int t2 = 0;
        int kend = offs[n + 1];
        for (int k = offs[n]; k < kend; ++k) {
            int rec = lists[k];
            int s = rec & 511;
            int m = (rec >> 9) & 63;
            int j = rec >> 15;
            int zs = z - s; if (zs < 0) zs += Z_;
            t2 += decode2((unsigned)stateg[zs * M_ + m], j);
        }
        tot[i] = (short)t2;
    }
    __syncthreads();

    for (int i = tid; i < ZN; i += NT) {
        int n = i / Z_;
        int z = i - n * Z_;
        outb[i] = xab[z * N_ + n] + 0.5f * (float)tot[z * N_ + n];
    }
}

extern "C" void kernel_launch(void* const* d_in, const int* in_sizes, int n_in,
                              void* d_out, int out_size, void* d_ws, size_t ws_size,
                              hipStream_t stream) {
    const float* xa = (const float*)d_in[0];
    const float* cw = (const float*)d_in[1];
    const int* vn   = (const int*)d_in[2];
    // d_in[3] = cn_idx: repeat(arange(M), dc) by construction — implicit.
    const int* sh   = (const int*)d_in[4];
    // d_in[5] = M (device scalar) — fixed at 46 for this problem.
    int iters = in_sizes[1];
    float* outp = (float*)d_out;

    const size_t lt_bytes = (size_t)B_ * ZN * sizeof(float);   // ~3.35 MB
    if (ws_size >= lt_bytes) {
        float* lt = (float*)d_ws;
        void* args[] = { (void*)&xa, (void*)&cw, (void*)&vn, (void*)&sh,
                         (void*)&outp, (void*)&lt, (void*)&iters };
        hipLaunchCooperativeKernel((const void*)ldpc_coop_kernel,
                                   dim3(B_ * CHUNKS), dim3(NT), args, 0, stream);
    } else {
        hipLaunchKernelGGL(ldpc_decode_kernel, dim3(B_), dim3(NT), 0, stream,
                           xa, cw, vn, sh, outp, iters);
    }
}

// Round 3
// 401.447 us; speedup vs baseline: 2.5152x; 2.0277x over previous
//
#include <hip/hip_runtime.h>

// Boosted neural LDPC min-sum decoder, MI355X — multi-kernel stream-sync version.
// Sizes fixed by setup_inputs(): B=32, Z=384, N=68, M=46, dc=7, E=322, iters=8.
#define B_   32
#define Z_   384
#define N_   68
#define M_   46
#define DC_  7
#define E_   (M_ * DC_)      // 322
#define ZN   (Z_ * N_)       // 26112
#define ZM   (Z_ * M_)       // 17664
#define W_   16              // padded gather width for pass A (dv avg 4.7)
#define INIT_STATE ((16u << 10) | (16u << 15))   // q1=0, q2=0 -> all c2v decode to 0

// ---- workspace layout (int32 offsets) ----
#define LT_OFF    0                         // float lt[B*ZN]
#define ST_OFF    (B_ * ZN)                 // int   state[B*ZM]
#define EVS_OFF   (ST_OFF + B_ * ZM)        // int   evs[E]      vn | s<<7
#define PL_OFF    (EVS_OFF + E_)            // int   plist[N*W]  s | m<<9 | j<<15 | valid<<18
#define DV_OFF    (PL_OFF + N_ * W_)        // int   dv[N]
#define OFFS_OFF  (DV_OFF + N_)             // int   offs[N+1]   (CSR, for rare tail)
#define LST_OFF   (OFFS_OFF + N_ + 1)       // int   lists[E]
#define WS_INTS   (LST_OFF + E_)            // ~1.40M ints = 5.61 MB

// state word layout (20 bits):
//  [0:6] neg bits | [7:9] first-min edge | [10:14] q1*2+16 | [15:19] q2*2+16
__device__ __forceinline__ int decode2(unsigned st, int j) {
    int neg   = (st >> j) & 1;
    int q1    = (int)((st >> 10) & 31) - 16;
    int q2    = (int)((st >> 15) & 31) - 16;
    int first = (int)((st >> 7) & 7);
    int q     = (j == first) ? q2 : q1;
    int par   = (__popc(st & 127u) - neg) & 1;   // parity of other edges' signs
    return par ? -q : q;                          // message * 2 (exact int)
}

// ==================== table-build kernel (1 block, once per launch) ====================
__global__ __launch_bounds__(1024)
void k_tables(const int* __restrict__ vn_idx, const int* __restrict__ shifts,
              int* __restrict__ ws)
{
    __shared__ int evs[E_];
    __shared__ int offs[N_ + 1];
    __shared__ int lists[E_];
    const int tid = threadIdx.x;
    if (tid < E_) evs[tid] = vn_idx[tid] | (shifts[tid] << 7);
    __syncthreads();
    if (tid < N_) {
        int c = 0;
        for (int e = 0; e < E_; ++e) c += ((evs[e] & 127) == tid);
        offs[tid + 1] = c;
    }
    if (tid == 0) offs[0] = 0;
    __syncthreads();
    if (tid == 0) {
        for (int n = 0; n < N_; ++n) offs[n + 1] += offs[n];
    }
    __syncthreads();
    if (tid < N_) {
        int p = offs[tid];
        for (int e = 0; e < E_; ++e) {
            int rec = evs[e];
            if ((rec & 127) == tid) {
                int s = rec >> 7;
                lists[p++] = s | ((e / DC_) << 9) | ((e % DC_) << 15);
            }
        }
    }
    __syncthreads();
    if (tid < E_) { ws[EVS_OFF + tid] = evs[tid]; ws[LST_OFF + tid] = lists[tid]; }
    if (tid < N_ + 1) ws[OFFS_OFF + tid] = offs[tid];
    if (tid < N_) ws[DV_OFF + tid] = offs[tid + 1] - offs[tid];
    for (int i = tid; i < N_ * W_; i += 1024) {
        int n = i / W_, k = i - n * W_;
        int dv = offs[n + 1] - offs[n];
        // dummy slots: s=0,m=0,j=0,valid=0 -> safe load, masked add
        ws[PL_OFF + i] = (k < dv) ? (lists[offs[n] + k] | (1 << 18)) : 0;
    }
}

// ==================== pass B: check-node update ====================
// thread i = b*ZM + z*M + m. Reads lt (or xa at it=0) + its OWN old state word.
__global__ __launch_bounds__(256)
void k_passB(const float* __restrict__ xa, const float* __restrict__ cw,
             const int* __restrict__ ws_tbl, int* __restrict__ state,
             const float* __restrict__ lt, int it, int use_xa)
{
    __shared__ int evs[E_];
    const int tid = threadIdx.x;
    for (int i = tid; i < E_; i += 256) evs[i] = ws_tbl[EVS_OFF + i];
    __syncthreads();

    const int i = blockIdx.x * 256 + tid;        // exact: grid*256 == B*ZM
    const int b = i / ZM;
    const int r = i - b * ZM;
    const int z = r / M_;
    const int m = r - z * M_;
    const float* src = (use_xa ? xa : lt) + (size_t)b * ZN;
    const unsigned st = use_xa ? INIT_STATE : (unsigned)state[i];
    const float w = cw[it];

    float m1 = 1e30f, m2 = 1e30f;
    int f = 0, negb = 0;
    #pragma unroll
    for (int j = 0; j < DC_; ++j) {
        int rec = evs[m * DC_ + j];
        int vn = rec & 127;
        int s  = rec >> 7;
        int zr = z + s; if (zr >= Z_) zr -= Z_;
        int c2 = decode2(st, j);
        // identical operand order to JAX: fl(fl(llr + tot) - c2v), then clip
        float v = src[zr * N_ + vn] - 0.5f * (float)c2;
        v = fminf(fmaxf(v, -20.0f), 20.0f);
        negb |= (v < 0.0f) << j;
        float a = fabsf(v);
        if (a < m1) { m2 = m1; m1 = a; f = j; }
        else if (a < m2) { m2 = a; }
    }
    // quantize-STE forward: clip(rint(2*w*min)/2, +-7.5), stored as int*2
    float r1 = fminf(fmaxf(rintf(w * m1 * 2.0f), -15.0f), 15.0f);
    float r2 = fminf(fmaxf(rintf(w * m2 * 2.0f), -15.0f), 15.0f);
    int q1 = (int)r1 + 16;
    int q2 = (int)r2 + 16;
    state[i] = (int)(unsigned)(negb | (f << 7) | (q1 << 10) | (q2 << 15));
}

// ==================== pass A: variable totals ====================
// thread i = b*ZN + z*N + n. Fixed-width W unrolled gather -> 16 independent loads.
__global__ __launch_bounds__(256)
void k_passA(const float* __restrict__ xa, const int* __restrict__ ws_tbl,
             const int* __restrict__ state, float* __restrict__ lt,
             float* __restrict__ out, int final_out)
{
    __shared__ int plist[N_ * W_];
    __shared__ int dvs[N_];
    const int tid = threadIdx.x;
    for (int i = tid; i < N_ * W_; i += 256) plist[i] = ws_tbl[PL_OFF + i];
    if (tid < N_) dvs[tid] = ws_tbl[DV_OFF + tid];
    __syncthreads();

    const int i = blockIdx.x * 256 + tid;        // exact: grid*256 == B*ZN
    const int b = i / ZN;
    const int r = i - b * ZN;
    const int z = r / N_;
    const int n = r - z * N_;
    const int* stb = state + (size_t)b * ZM;

    int t2 = 0;
    #pragma unroll
    for (int k = 0; k < W_; ++k) {
        int rec = plist[n * W_ + k];
        int s = rec & 511;
        int m = (rec >> 9) & 63;
        int j = (rec >> 15) & 7;
        int zs = z - s; if (zs < 0) zs += Z_;
        int val = decode2((unsigned)stb[zs * M_ + m], j);
        t2 += (rec >> 18) ? val : 0;             // masked add; load was safe/unconditional
    }
    int dvn = dvs[n];
    if (dvn > W_) {                               // rare tail (dv>16 ~ never at E/N=4.7)
        int o = ws_tbl[OFFS_OFF + n];
        for (int k = W_; k < dvn; ++k) {
            int rec = ws_tbl[LST_OFF + o + k];
            int s = rec & 511;
            int m = (rec >> 9) & 63;
            int j = (rec >> 15) & 7;
            int zs = z - s; if (zs < 0) zs += Z_;
            t2 += decode2((unsigned)stb[zs * M_ + m], j);
        }
    }
    float val = xa[i] + 0.5f * (float)t2;        // fl(llr + tot), exact int tot
    if (final_out) out[(size_t)b * ZN + n * Z_ + z] = val;
    else           lt[(size_t)b * ZN + r] = val;
}

// iters==0 corner: out = transpose(xa)
__global__ __launch_bounds__(256)
void k_transpose(const float* __restrict__ xa, float* __restrict__ out)
{
    const int i = blockIdx.x * 256 + threadIdx.x;
    const int b = i / ZN;
    const int r = i - b * ZN;
    const int z = r / N_;
    const int n = r - z * N_;
    out[(size_t)b * ZN + n * Z_ + z] = xa[i];
}

// ==================== fallback: round-1 single-block-per-batch kernel ====================
__global__ __launch_bounds__(1024)
void ldpc_decode_kernel(const float* __restrict__ xa,
                        const float* __restrict__ cw,
                        const int*   __restrict__ vn_idx,
                        const int*   __restrict__ shifts,
                        float* out, int iters)
{
    __shared__ short tot[ZN];
    __shared__ int   evs[E_];
    __shared__ int   offs[N_ + 1];
    __shared__ int   lists[E_];
    __shared__ float wlds[8];

    const int tid = threadIdx.x;
    const int b   = blockIdx.x;
    const float* xab = xa + (size_t)b * ZN;
    float* outb = out + (size_t)b * ZN;
    int* stateg = (int*)outb;

    if (tid < E_) evs[tid] = vn_idx[tid] | (shifts[tid] << 7);
    if (tid < iters && tid < 8) wlds[tid] = cw[tid];
    __syncthreads();
    if (tid < N_) {
        int c = 0;
        for (int e = 0; e < E_; ++e) c += ((evs[e] & 127) == tid);
        offs[tid + 1] = c;
    }
    if (tid == 0) offs[0] = 0;
    __syncthreads();
    if (tid == 0) { for (int n = 0; n < N_; ++n) offs[n + 1] += offs[n]; }
    __syncthreads();
    if (tid < N_) {
        int p = offs[tid];
        for (int e = 0; e < E_; ++e) {
            int rec = evs[e];
            if ((rec & 127) == tid) {
                int s = rec >> 7;
                lists[p++] = s | ((e / DC_) << 9) | ((e % DC_) << 15);
            }
        }
    }
    __syncthreads();

    for (int i = tid; i < ZM; i += 1024) stateg[i] = (int)INIT_STATE;
    __syncthreads();

    for (int it = 0; it < iters; ++it) {
        for (int i = tid; i < ZN; i += 1024) {
            int z = i / N_, n = i - z * N_, t2 = 0;
            int kend = offs[n + 1];
            for (int k = offs[n]; k < kend; ++k) {
                int rec = lists[k];
                int s = rec & 511, m = (rec >> 9) & 63, j = rec >> 15;
                int zs = z - s; if (zs < 0) zs += Z_;
                t2 += decode2((unsigned)stateg[zs * M_ + m], j);
            }
            tot[i] = (short)t2;
        }
        __syncthreads();
        const float w = wlds[it];
        for (int i = tid; i < ZM; i += 1024) {
            int z = i / M_, m = i - z * M_;
            unsigned st = (unsigned)stateg[i];
            float m1 = 1e30f, m2 = 1e30f;
            int f = 0, negb = 0;
            #pragma unroll
            for (int j = 0; j < DC_; ++j) {
                int rec = evs[m * DC_ + j];
                int vn = rec & 127, s = rec >> 7;
                int zr = z + s; if (zr >= Z_) zr -= Z_;
                int c2 = decode2(st, j);
                int idx = zr * N_ + vn;
                float v = (xab[idx] + 0.5f * (float)tot[idx]) - 0.5f * (float)c2;
                v = fminf(fmaxf(v, -20.0f), 20.0f);
                negb |= (v < 0.0f) << j;
                float a = fabsf(v);
                if (a < m1) { m2 = m1; m1 = a; f = j; }
                else if (a < m2) { m2 = a; }
            }
            float r1 = fminf(fmaxf(rintf(w * m1 * 2.0f), -15.0f), 15.0f);
            float r2 = fminf(fmaxf(rintf(w * m2 * 2.0f), -15.0f), 15.0f);
            stateg[i] = (int)(unsigned)(negb | (f << 7) | (((int)r1 + 16) << 10) | (((int)r2 + 16) << 15));
        }
        __syncthreads();
    }

    for (int i = tid; i < ZN; i += 1024) {
        int z = i / N_, n = i - z * N_, t2 = 0;
        int kend = offs[n + 1];
        for (int k = offs[n]; k < kend; ++k) {
            int rec = lists[k];
            int s = rec & 511, m = (rec >> 9) & 63, j = rec >> 15;
            int zs = z - s; if (zs < 0) zs += Z_;
            t2 += decode2((unsigned)stateg[zs * M_ + m], j);
        }
        tot[i] = (short)t2;
    }
    __syncthreads();
    for (int i = tid; i < ZN; i += 1024) {
        int n = i / Z_, z = i - n * Z_;
        outb[i] = xab[z * N_ + n] + 0.5f * (float)tot[z * N_ + n];
    }
}

extern "C" void kernel_launch(void* const* d_in, const int* in_sizes, int n_in,
                              void* d_out, int out_size, void* d_ws, size_t ws_size,
                              hipStream_t stream) {
    const float* xa = (const float*)d_in[0];
    const float* cw = (const float*)d_in[1];
    const int* vn   = (const int*)d_in[2];
    // d_in[3] = cn_idx: repeat(arange(M), dc) by construction — implicit.
    const int* sh   = (const int*)d_in[4];
    int iters = in_sizes[1];
    float* outp = (float*)d_out;

    if (ws_size >= (size_t)WS_INTS * sizeof(int)) {
        int*   ws    = (int*)d_ws;
        float* lt    = (float*)d_ws;        // LT_OFF == 0
        int*   state = ws + ST_OFF;

        hipLaunchKernelGGL(k_tables, dim3(1), dim3(1024), 0, stream, vn, sh, ws);
        if (iters == 0) {
            hipLaunchKernelGGL(k_transpose, dim3(B_ * ZN / 256), dim3(256), 0, stream, xa, outp);
            return;
        }
        hipLaunchKernelGGL(k_passB, dim3(B_ * ZM / 256), dim3(256), 0, stream,
                           xa, cw, ws, state, lt, 0, 1);
        for (int it = 1; it < iters; ++it) {
            hipLaunchKernelGGL(k_passA, dim3(B_ * ZN / 256), dim3(256), 0, stream,
                               xa, ws, state, lt, outp, 0);
            hipLaunchKernelGGL(k_passB, dim3(B_ * ZM / 256), dim3(256), 0, stream,
                               xa, cw, ws, state, lt, it, 0);
        }
        hipLaunchKernelGGL(k_passA, dim3(B_ * ZN / 256), dim3(256), 0, stream,
                           xa, ws, state, lt, outp, 1);
    } else {
        hipLaunchKernelGGL(ldpc_decode_kernel, dim3(B_), dim3(1024), 0, stream,
                           xa, cw, vn, sh, outp, iters);
    }
}

// Round 4
// 250.547 us; speedup vs baseline: 4.0301x; 1.6023x over previous
//
#include <hip/hip_runtime.h>

// Boosted neural LDPC min-sum decoder, MI355X — z-fastest coalesced layout.
// Sizes fixed by setup_inputs(): B=32, Z=384, N=68, M=46, dc=7, E=322, iters=8.
#define B_   32
#define Z_   384
#define N_   68
#define M_   46
#define DC_  7
#define E_   (M_ * DC_)      // 322
#define ZN   (Z_ * N_)       // 26112
#define ZM   (Z_ * M_)       // 17664
#define INIT_STATE ((16u << 10) | (16u << 15))   // q1=0, q2=0 -> all c2v decode to 0

// ---- workspace layout (int32 offsets) ----
// All big arrays are z-fastest: xat[b][n][z], lt[b][n][z], state[b][m][z].
#define XAT_OFF   0                          // float xat[B*ZN]
#define LT_OFF    (B_ * ZN)                  // float lt[B*ZN]
#define ST_OFF    (LT_OFF + B_ * ZN)         // int   state[B*ZM]
#define EVS_OFF   (ST_OFF + B_ * ZM)         // int   evs[E]     vn | s<<7   (check-major)
#define OFFS_OFF  (EVS_OFF + E_)             // int   offs[N+1]  CSR per variable
#define LST_OFF   (OFFS_OFF + N_ + 1)        // int   lists[E]   s | m<<9 | j<<15
#define WS_INTS   (LST_OFF + E_)             // ~2.24M ints = 8.96 MB

// state word layout (20 bits):
//  [0:6] neg bits | [7:9] first-min edge | [10:14] q1*2+16 | [15:19] q2*2+16
__device__ __forceinline__ int decode2(unsigned st, int j) {
    int neg   = (st >> j) & 1;
    int q1    = (int)((st >> 10) & 31) - 16;
    int q2    = (int)((st >> 15) & 31) - 16;
    int first = (int)((st >> 7) & 7);
    int q     = (j == first) ? q2 : q1;
    int par   = (__popc(st & 127u) - neg) & 1;   // parity of other edges' signs
    return par ? -q : q;                          // message * 2 (exact int)
}

// ==================== table-build kernel (1 block, once per launch) ====================
__global__ __launch_bounds__(1024)
void k_tables(const int* __restrict__ vn_idx, const int* __restrict__ shifts,
              int* __restrict__ ws)
{
    __shared__ int evs[E_];
    __shared__ int offs[N_ + 1];
    __shared__ int lists[E_];
    const int tid = threadIdx.x;
    if (tid < E_) evs[tid] = vn_idx[tid] | (shifts[tid] << 7);
    __syncthreads();
    if (tid < N_) {
        int c = 0;
        for (int e = 0; e < E_; ++e) c += ((evs[e] & 127) == tid);
        offs[tid + 1] = c;
    }
    if (tid == 0) offs[0] = 0;
    __syncthreads();
    if (tid == 0) { for (int n = 0; n < N_; ++n) offs[n + 1] += offs[n]; }
    __syncthreads();
    if (tid < N_) {
        int p = offs[tid];
        for (int e = 0; e < E_; ++e) {
            int rec = evs[e];
            if ((rec & 127) == tid) {
                int s = rec >> 7;
                lists[p++] = s | ((e / DC_) << 9) | ((e % DC_) << 15);
            }
        }
    }
    __syncthreads();
    if (tid < E_) { ws[EVS_OFF + tid] = evs[tid]; ws[LST_OFF + tid] = lists[tid]; }
    if (tid < N_ + 1) ws[OFFS_OFF + tid] = offs[tid];
}

// ==================== pre-transpose: xat[b][n][z] = xa[b][z][n] ====================
// Block handles one (b, 64-row z-tile). Coalesced global read + coalesced write.
__global__ __launch_bounds__(256)
void k_pre(const float* __restrict__ xa, float* __restrict__ xat)
{
    __shared__ float tile[N_ * 65];           // [n][zl], pad 65 to break conflicts
    const int b  = blockIdx.x / 6;
    const int t  = blockIdx.x - b * 6;
    const int z0 = t * 64;
    const int tid = threadIdx.x;
    const float* src = xa + (size_t)b * ZN + (size_t)z0 * N_;
    for (int i = tid; i < 64 * N_; i += 256) {  // contiguous 17 KB read
        int r = i / N_, n = i - r * N_;
        tile[n * 65 + r] = src[i];
    }
    __syncthreads();
    float* dst = xat + (size_t)b * ZN + z0;
    for (int i = tid; i < 64 * N_; i += 256) {
        int n = i >> 6, zl = i & 63;
        dst[n * Z_ + zl] = tile[n * 65 + zl];
    }
}

// ==================== pass B: check-node update ====================
// block = (b, m), thread = z. All loads/stores coalesced; edge data block-uniform.
__global__ __launch_bounds__(384)
void k_passB(const float* __restrict__ cw, const int* __restrict__ ws_tbl,
             int* __restrict__ state, const float* __restrict__ src_g,
             int it, int use_init)
{
    __shared__ int cevs[DC_];
    const int b = blockIdx.x / M_;
    const int m = blockIdx.x - b * M_;
    const int z = threadIdx.x;
    if (z < DC_) cevs[z] = ws_tbl[EVS_OFF + m * DC_ + z];
    __syncthreads();

    const float* src = src_g + (size_t)b * ZN;   // xat at it=0, lt otherwise
    int* stp = state + (size_t)b * ZM + m * Z_;
    const unsigned st = use_init ? INIT_STATE : (unsigned)stp[z];
    const float w = cw[it];

    float m1 = 1e30f, m2 = 1e30f;
    int f = 0, negb = 0;
    #pragma unroll
    for (int j = 0; j < DC_; ++j) {
        int rec = cevs[j];
        int vn = rec & 127;
        int s  = rec >> 7;
        int zr = z + s; if (zr >= Z_) zr -= Z_;
        int c2 = decode2(st, j);
        // identical operand order to JAX: fl(fl(llr + tot) - c2v), then clip
        float v = src[vn * Z_ + zr] - 0.5f * (float)c2;
        v = fminf(fmaxf(v, -20.0f), 20.0f);
        negb |= (v < 0.0f) << j;
        float a = fabsf(v);
        if (a < m1) { m2 = m1; m1 = a; f = j; }
        else if (a < m2) { m2 = a; }
    }
    // quantize-STE forward: clip(rint(2*w*min)/2, +-7.5), stored as int*2
    float r1 = fminf(fmaxf(rintf(w * m1 * 2.0f), -15.0f), 15.0f);
    float r2 = fminf(fmaxf(rintf(w * m2 * 2.0f), -15.0f), 15.0f);
    int q1 = (int)r1 + 16;
    int q2 = (int)r2 + 16;
    stp[z] = (int)(unsigned)(negb | (f << 7) | (q1 << 10) | (q2 << 15));
}

// ==================== pass A: variable totals ====================
// block = (b, n), thread = z. Gathers are coalesced (consecutive z per edge).
__global__ __launch_bounds__(384)
void k_passA(const float* __restrict__ xat, const int* __restrict__ ws_tbl,
             const int* __restrict__ state, float* __restrict__ dst)
{
    __shared__ int vlist[E_];                 // dv entries actually used (dv << E)
    __shared__ int s_cnt;
    const int b = blockIdx.x / N_;
    const int n = blockIdx.x - b * N_;
    const int z = threadIdx.x;
    const int tid = threadIdx.x;
    if (tid == 0) s_cnt = ws_tbl[OFFS_OFF + n + 1] - ws_tbl[OFFS_OFF + n];
    {
        int o = ws_tbl[OFFS_OFF + n];
        int e = ws_tbl[OFFS_OFF + n + 1];
        for (int k = o + tid; k < e; k += 384) vlist[k - o] = ws_tbl[LST_OFF + k];
    }
    __syncthreads();

    const int* stb = state + (size_t)b * ZM;
    const int cnt = s_cnt;
    int t2 = 0;
    for (int k = 0; k < cnt; ++k) {           // wave-uniform trip count
        int rec = vlist[k];
        int s = rec & 511;
        int m = (rec >> 9) & 63;
        int j = (rec >> 15) & 7;
        int zs = z - s; if (zs < 0) zs += Z_;
        t2 += decode2((unsigned)stb[m * Z_ + zs], j);
    }
    // fl(llr + tot): tot exact int in half-steps
    dst[(size_t)b * ZN + n * Z_ + z] = xat[(size_t)b * ZN + n * Z_ + z] + 0.5f * (float)t2;
}

// ==================== fallback: single-block-per-batch kernel (small ws) ====================
__global__ __launch_bounds__(1024)
void ldpc_decode_kernel(const float* __restrict__ xa,
                        const float* __restrict__ cw,
                        const int*   __restrict__ vn_idx,
                        const int*   __restrict__ shifts,
                        float* out, int iters)
{
    __shared__ short tot[ZN];
    __shared__ int   evs[E_];
    __shared__ int   offs[N_ + 1];
    __shared__ int   lists[E_];
    __shared__ float wlds[8];

    const int tid = threadIdx.x;
    const int b   = blockIdx.x;
    const float* xab = xa + (size_t)b * ZN;
    float* outb = out + (size_t)b * ZN;
    int* stateg = (int*)outb;

    if (tid < E_) evs[tid] = vn_idx[tid] | (shifts[tid] << 7);
    if (tid < iters && tid < 8) wlds[tid] = cw[tid];
    __syncthreads();
    if (tid < N_) {
        int c = 0;
        for (int e = 0; e < E_; ++e) c += ((evs[e] & 127) == tid);
        offs[tid + 1] = c;
    }
    if (tid == 0) offs[0] = 0;
    __syncthreads();
    if (tid == 0) { for (int n = 0; n < N_; ++n) offs[n + 1] += offs[n]; }
    __syncthreads();
    if (tid < N_) {
        int p = offs[tid];
        for (int e = 0; e < E_; ++e) {
            int rec = evs[e];
            if ((rec & 127) == tid) {
                int s = rec >> 7;
                lists[p++] = s | ((e / DC_) << 9) | ((e % DC_) << 15);
            }
        }
    }
    __syncthreads();

    for (int i = tid; i < ZM; i += 1024) stateg[i] = (int)INIT_STATE;
    __syncthreads();

    for (int it = 0; it < iters; ++it) {
        for (int i = tid; i < ZN; i += 1024) {
            int z = i / N_, n = i - z * N_, t2 = 0;
            int kend = offs[n + 1];
            for (int k = offs[n]; k < kend; ++k) {
                int rec = lists[k];
                int s = rec & 511, m = (rec >> 9) & 63, j = rec >> 15;
                int zs = z - s; if (zs < 0) zs += Z_;
                t2 += decode2((unsigned)stateg[zs * M_ + m], j);
            }
            tot[i] = (short)t2;
        }
        __syncthreads();
        const float w = wlds[it];
        for (int i = tid; i < ZM; i += 1024) {
            int z = i / M_, m = i - z * M_;
            unsigned st = (unsigned)stateg[i];
            float m1 = 1e30f, m2 = 1e30f;
            int f = 0, negb = 0;
            #pragma unroll
            for (int j = 0; j < DC_; ++j) {
                int rec = evs[m * DC_ + j];
                int vn = rec & 127, s = rec >> 7;
                int zr = z + s; if (zr >= Z_) zr -= Z_;
                int c2 = decode2(st, j);
                int idx = zr * N_ + vn;
                float v = (xab[idx] + 0.5f * (float)tot[idx]) - 0.5f * (float)c2;
                v = fminf(fmaxf(v, -20.0f), 20.0f);
                negb |= (v < 0.0f) << j;
                float a = fabsf(v);
                if (a < m1) { m2 = m1; m1 = a; f = j; }
                else if (a < m2) { m2 = a; }
            }
            float r1 = fminf(fmaxf(rintf(w * m1 * 2.0f), -15.0f), 15.0f);
            float r2 = fminf(fmaxf(rintf(w * m2 * 2.0f), -15.0f), 15.0f);
            stateg[i] = (int)(unsigned)(negb | (f << 7) | (((int)r1 + 16) << 10) | (((int)r2 + 16) << 15));
        }
        __syncthreads();
    }

    for (int i = tid; i < ZN; i += 1024) {
        int z = i / N_, n = i - z * N_, t2 = 0;
        int kend = offs[n + 1];
        for (int k = offs[n]; k < kend; ++k) {
            int rec = lists[k];
            int s = rec & 511, m = (rec >> 9) & 63, j = rec >> 15;
            int zs = z - s; if (zs < 0) zs += Z_;
            t2 += decode2((unsigned)stateg[zs * M_ + m], j);
        }
        tot[i] = (short)t2;
    }
    __syncthreads();
    for (int i = tid; i < ZN; i += 1024) {
        int n = i / Z_, z = i - n * Z_;
        outb[i] = xab[z * N_ + n] + 0.5f * (float)tot[z * N_ + n];
    }
}

extern "C" void kernel_launch(void* const* d_in, const int* in_sizes, int n_in,
                              void* d_out, int out_size, void* d_ws, size_t ws_size,
                              hipStream_t stream) {
    const float* xa = (const float*)d_in[0];
    const float* cw = (const float*)d_in[1];
    const int* vn   = (const int*)d_in[2];
    // d_in[3] = cn_idx: repeat(arange(M), dc) by construction — implicit.
    const int* sh   = (const int*)d_in[4];
    int iters = in_sizes[1];
    float* outp = (float*)d_out;

    if (ws_size >= (size_t)WS_INTS * sizeof(int)) {
        int*   ws    = (int*)d_ws;
        float* xat   = (float*)d_ws + XAT_OFF;
        float* lt    = (float*)d_ws + LT_OFF;
        int*   state = ws + ST_OFF;

        if (iters == 0) {   // out = transpose(xa)
            hipLaunchKernelGGL(k_pre, dim3(B_ * 6), dim3(256), 0, stream, xa, outp);
            return;
        }
        hipLaunchKernelGGL(k_tables, dim3(1), dim3(1024), 0, stream, vn, sh, ws);
        hipLaunchKernelGGL(k_pre, dim3(B_ * 6), dim3(256), 0, stream, xa, xat);
        // it = 0: tot == 0, lt == xat
        hipLaunchKernelGGL(k_passB, dim3(B_ * M_), dim3(Z_), 0, stream,
                           cw, ws, state, xat, 0, 1);
        for (int it = 1; it < iters; ++it) {
            hipLaunchKernelGGL(k_passA, dim3(B_ * N_), dim3(Z_), 0, stream,
                               xat, ws, state, lt);
            hipLaunchKernelGGL(k_passB, dim3(B_ * M_), dim3(Z_), 0, stream,
                               cw, ws, state, lt, it, 0);
        }
        hipLaunchKernelGGL(k_passA, dim3(B_ * N_), dim3(Z_), 0, stream,
                           xat, ws, state, outp);
    } else {
        hipLaunchKernelGGL(ldpc_decode_kernel, dim3(B_), dim3(1024), 0, stream,
                           xa, cw, vn, sh, outp, iters);
    }
}